// Round 2
// baseline (150.774 us; speedup 1.0000x reference)
//
#include <hip/hip_runtime.h>
#include <math.h>

#define BB 2
#define NN 8192
#define JSPLIT 8
#define TJ 1024          // LDS staging tile (float4 = 16KB)

// ws layout (floats):
// [0..64)    acc: per-sample 32 floats
// [64..66)   ccount[2] (uint) compaction counters
// [80..80+BB*NN*4)            cdata float4 per compacted point
// then pm [BB*NN]
// then partial [JSPLIT][BB][NN][3]
#define ACC_OFF 0
#define CNT_OFF 64
#define CDATA_OFF 80
#define PM_OFF (CDATA_OFF + BB * NN * 4)
#define PARTIAL_OFF (PM_OFF + BB * NN)

// acc layout per sample:
// 0 ref_sum, 1 con_sum, 2 n_pred, 3 spx, 4 spy, 5 spz, 6 n_gt, 7 bm_sum,
// 8..13 cov(xx,xy,xz,yy,yz,zz), 14 sum_dm, 15 sum_d2m, 16 max_dm(bits),
// 17 smooth_num, 18 smooth_den

__device__ __forceinline__ float wave_sum(float v) {
#pragma unroll
    for (int o = 32; o > 0; o >>= 1) v += __shfl_xor(v, o, 64);
    return v;
}

__device__ __forceinline__ void wave_atomic_add(float* addr, float v) {
    v = wave_sum(v);
    if ((threadIdx.x & 63) == 0) atomicAdd(addr, v);
}

__device__ __forceinline__ void wave_atomic_max_nonneg(float* addr, float v) {
#pragma unroll
    for (int o = 32; o > 0; o >>= 1) v = fmaxf(v, __shfl_xor(v, o, 64));
    if ((threadIdx.x & 63) == 0) atomicMax((unsigned int*)addr, __float_as_uint(v));
}

__global__ void kz(float* ws) {
    int t = threadIdx.x;
    if (t < BB * 32) ws[ACC_OFF + t] = 0.f;
    if (t < BB) ((unsigned int*)(ws + CNT_OFF))[t] = 0u;
}

__global__ void k1(const float* __restrict__ logits, const float* __restrict__ olog,
                   const float* __restrict__ h, const int* __restrict__ tgt,
                   const float* __restrict__ pts, float* __restrict__ ws) {
    int gid = blockIdx.x * 256 + threadIdx.x;   // over BB*NN
    int b = gid / NN;

    const float* L = logits + (size_t)gid * 3;
    float l0 = L[0], l1 = L[1], l2 = L[2];
    const float* O = olog + (size_t)gid * 3;
    float o0 = O[0], o1 = O[1], o2 = O[2];
    float hp = h[gid];
    int t = tgt[gid];
    const float* P = pts + (size_t)gid * 3;
    float px = P[0], py = P[1], pz = P[2];

    // softmax + log-softmax of logits
    float m = fmaxf(l0, fmaxf(l1, l2));
    float e0 = expf(l0 - m), e1 = expf(l1 - m), e2 = expf(l2 - m);
    float s = e0 + e1 + e2;
    float inv = 1.f / s;
    float p0 = e0 * inv, p1 = e1 * inv, p2 = e2 * inv;
    float ls = logf(s);
    float lt = (t == 0) ? l0 : ((t == 1) ? l1 : l2);
    float nll = -(lt - m - ls);

    // softmax of original logits
    float mo = fmaxf(o0, fmaxf(o1, o2));
    float f0 = expf(o0 - mo), f1 = expf(o1 - mo), f2 = expf(o2 - mo);
    float so = 1.f / (f0 + f1 + f2);
    float q0 = f0 * so, q1 = f1 * so, q2 = f2 * so;

    float con = (p0 - q0) * (p0 - q0) + (p1 - q1) * (p1 - q1) + (p2 - q2) * (p2 - q2);

    float bm = (hp > 0.3f && hp < 0.7f) ? 1.f : 0.f;
    float w = 1.f + bm;
    float refc = nll * w;

    float pred = (l2 > l0 && l2 > l1) ? 1.f : 0.f;
    float gt = (t == 2) ? 1.f : 0.f;

    // compact boundary points for the pairwise kernel
    if (bm > 0.f) {
        unsigned int idx = atomicAdd(((unsigned int*)(ws + CNT_OFF)) + b, 1u);
        float4* cd = (float4*)(ws + CDATA_OFF);
        cd[(size_t)b * NN + idx] = make_float4(px, py, pz, p2);
    }
    ws[PM_OFF + gid] = pred;

    float* a = ws + ACC_OFF + b * 32;
    wave_atomic_add(a + 0, refc);
    wave_atomic_add(a + 1, con);
    wave_atomic_add(a + 2, pred);
    wave_atomic_add(a + 3, pred * px);
    wave_atomic_add(a + 4, pred * py);
    wave_atomic_add(a + 5, pred * pz);
    wave_atomic_add(a + 6, gt);
    wave_atomic_add(a + 7, bm);
}

__global__ void k2(const float* __restrict__ pts, float* __restrict__ ws) {
    int gid = blockIdx.x * 256 + threadIdx.x;
    int b = gid / NN;
    float* a = ws + ACC_OFF + b * 32;

    float n = a[2];
    float nz = fmaxf(n, 1.f);
    float cx = a[3] / nz, cy = a[4] / nz, cz = a[5] / nz;

    const float* P = pts + (size_t)gid * 3;
    float dx = P[0] - cx, dy = P[1] - cy, dz = P[2] - cz;
    float mM = ws[PM_OFF + gid];

    float mx = dx * mM, my = dy * mM, mz = dz * mM;
    float d = sqrtf(dx * dx + dy * dy + dz * dz + 1e-12f);
    float dm = d * mM;

    wave_atomic_add(a + 8,  mx * mx);
    wave_atomic_add(a + 9,  mx * my);
    wave_atomic_add(a + 10, mx * mz);
    wave_atomic_add(a + 11, my * my);
    wave_atomic_add(a + 12, my * mz);
    wave_atomic_add(a + 13, mz * mz);
    wave_atomic_add(a + 14, dm);
    wave_atomic_add(a + 15, d * dm);
    wave_atomic_max_nonneg(a + 16, dm);
}

// pairwise over compacted boundary points
__global__ void k3(float* __restrict__ ws) {
    int bid = blockIdx.x;
    int js = bid % JSPLIT;
    int ib = (bid / JSPLIT) % (NN / 256);
    int b  = bid / (JSPLIT * (NN / 256));

    int M = (int)((unsigned int*)(ws + CNT_OFF))[b];
    if (ib * 256 >= M) return;                       // uniform block exit
    int chunk = (M + JSPLIT - 1) / JSPLIT;
    int jbeg = js * chunk;
    if (jbeg >= M) return;                           // uniform block exit
    int jend = min(jbeg + chunk, M);

    const float4* cd = (const float4*)(ws + CDATA_OFF) + (size_t)b * NN;
    int i = ib * 256 + threadIdx.x;
    bool active = (i < M);

    float4 me = cd[active ? i : 0];
    float xi = active ? me.x : 1e9f;
    float yi = me.y, zi = me.z;

    __shared__ float4 sj[TJ];
    float cnt = 0.f, s1 = 0.f, s2 = 0.f;

    for (int j0 = jbeg; j0 < jend; j0 += TJ) {
        int count = min(TJ, jend - j0);
        __syncthreads();
        for (int k = threadIdx.x; k < count; k += 256) sj[k] = cd[j0 + k];
        __syncthreads();
#pragma unroll 4
        for (int k = 0; k < count; k++) {
            float4 v = sj[k];
            float dx = xi - v.x, dy = yi - v.y, dz = zi - v.z;
            float d2 = dx * dx + dy * dy + dz * dz;
            if (d2 < 0.0025f) { cnt += 1.f; s1 += v.w; s2 += v.w * v.w; }
        }
    }

    if (active) {
        float* p = ws + PARTIAL_OFF + ((size_t)js * BB * NN + (size_t)b * NN + i) * 3;
        p[0] = cnt; p[1] = s1; p[2] = s2;
    }
}

__global__ void k4(float* __restrict__ ws) {
    int gid = blockIdx.x * 256 + threadIdx.x;
    int b = gid / NN;
    int i = gid % NN;

    int M = (int)((unsigned int*)(ws + CNT_OFF))[b];
    if ((gid % NN) - threadIdx.x >= M) return;       // uniform: whole block beyond M
    bool active = (i < M);
    int chunk = (M + JSPLIT - 1) / JSPLIT;

    float cnt = 0.f, s1 = 0.f, s2 = 0.f;
#pragma unroll
    for (int js = 0; js < JSPLIT; js++) {
        if (js * chunk < M && active) {
            const float* p = ws + PARTIAL_OFF + ((size_t)js * BB * NN + (size_t)b * NN + i) * 3;
            cnt += p[0]; s1 += p[1]; s2 += p[2];
        }
    }
    float var = (s2 - s1 * s1 / fmaxf(cnt, 1.f)) / fmaxf(cnt - 1.f, 1.f);
    float valid = (active && cnt > 1.f) ? 1.f : 0.f;

    float* a = ws + ACC_OFF + b * 32;
    wave_atomic_add(a + 17, var * valid);
    wave_atomic_add(a + 18, valid);
}

__global__ void k5(const float* __restrict__ ws, float* __restrict__ out) {
    if (threadIdx.x != 0 || blockIdx.x != 0) return;
    double tot = 0.0;
    for (int b = 0; b < BB; b++) {
        const float* a = ws + ACC_OFF + b * 32;
        double refm = (double)a[0] / NN;
        double conm = (double)a[1] / (NN * 3);
        double n = a[2];
        double nz = fmax(n, 1.0);

        double shape = 0.0;
        if (n >= 10.0) {
            double cxx = a[8] / nz, cxy = a[9] / nz, cxz = a[10] / nz;
            double cyy = a[11] / nz, cyz = a[12] / nz, czz = a[13] / nz;
            double q = (cxx + cyy + czz) / 3.0;
            double p1 = cxy * cxy + cxz * cxz + cyz * cyz;
            double p2 = (cxx - q) * (cxx - q) + (cyy - q) * (cyy - q) + (czz - q) * (czz - q) + 2.0 * p1;
            double p = sqrt(fmax(p2, 0.0) / 6.0);
            double ev0, ev1, ev2;
            if (p < 1e-30) { ev0 = ev1 = ev2 = q; }
            else {
                double b00 = (cxx - q) / p, b11 = (cyy - q) / p, b22 = (czz - q) / p;
                double b01 = cxy / p, b02 = cxz / p, b12 = cyz / p;
                double det = b00 * (b11 * b22 - b12 * b12)
                           - b01 * (b01 * b22 - b12 * b02)
                           + b02 * (b01 * b12 - b11 * b02);
                double r = det / 2.0;
                r = fmin(1.0, fmax(-1.0, r));
                double phi = acos(r) / 3.0;
                double e1 = q + 2.0 * p * cos(phi);
                double e3 = q + 2.0 * p * cos(phi + 2.0943951023931953);
                double e2 = 3.0 * q - e1 - e3;
                ev2 = e1; ev1 = e2; ev0 = e3;
            }
            double aa = ev2 + 1e-8;
            double r1 = ev1 / aa - 1.0, r0 = ev0 / aa - 1.0;
            shape = r1 * r1 + r0 * r0;
        }

        double sdm = a[14], sd2m = a[15], maxd = a[16];
        double var = (sd2m - sdm * sdm / nz) / fmax(n - 1.0, 1.0);
        double conn = (n >= 5.0) ? var / (maxd + 1e-8) : 0.0;

        double sm = (a[7] >= 5.0) ? (double)a[17] / fmax((double)a[18], 1.0) : 0.0;

        double pv = a[2], gv = a[6];
        double vol = (pv - gv) * (pv - gv);
        double rel = fabs(pv - gv) / fmax(gv, 1.0);
        double size = (gv > 0.0) ? vol + 0.5 * rel : vol;

        tot += 0.3 * refm + 0.2 * conm + 0.5 * shape + 0.3 * sm + 0.8 * size + 0.6 * conn;
    }
    out[0] = (float)(tot / BB);
}

extern "C" void kernel_launch(void* const* d_in, const int* in_sizes, int n_in,
                              void* d_out, int out_size, void* d_ws, size_t ws_size,
                              hipStream_t stream) {
    const float* logits = (const float*)d_in[0];
    const float* olog   = (const float*)d_in[1];
    const float* h      = (const float*)d_in[2];
    const int*   tgt    = (const int*)d_in[3];
    const float* pts    = (const float*)d_in[4];
    float* out = (float*)d_out;
    float* ws  = (float*)d_ws;

    kz<<<1, 64, 0, stream>>>(ws);
    k1<<<BB * NN / 256, 256, 0, stream>>>(logits, olog, h, tgt, pts, ws);
    k2<<<BB * NN / 256, 256, 0, stream>>>(pts, ws);
    k3<<<BB * (NN / 256) * JSPLIT, 256, 0, stream>>>(ws);
    k4<<<BB * NN / 256, 256, 0, stream>>>(ws);
    k5<<<1, 64, 0, stream>>>(ws, out);
}

// Round 3
// 88.171 us; speedup vs baseline: 1.7100x; 1.7100x over previous
//
#include <hip/hip_runtime.h>
#include <math.h>

#define BB 2
#define NN 8192
#define JSPLIT 8
#define TJ 1024          // LDS staging tile (float4 = 16KB)

// ws layout (floats):
#define ACC_OFF 0
#define CNT_OFF 64
#define CDATA_OFF 80
#define PM_OFF (CDATA_OFF + BB * NN * 4)
#define PARTIAL_OFF (PM_OFF + BB * NN)

// acc layout per sample:
// 0 ref_sum, 1 con_sum, 2 n_pred, 3 spx, 4 spy, 5 spz, 6 n_gt, 7 bm_sum,
// 8..13 cov(xx,xy,xz,yy,yz,zz), 14 sum_dm, 15 sum_d2m, 16 max_dm(bits),
// 17 smooth_num, 18 smooth_den

__device__ __forceinline__ float wave_sum(float v) {
#pragma unroll
    for (int o = 32; o > 0; o >>= 1) v += __shfl_xor(v, o, 64);
    return v;
}

__device__ __forceinline__ void wave_atomic_add(float* addr, float v) {
    v = wave_sum(v);
    if ((threadIdx.x & 63) == 0) atomicAdd(addr, v);
}

__device__ __forceinline__ void wave_atomic_max_nonneg(float* addr, float v) {
#pragma unroll
    for (int o = 32; o > 0; o >>= 1) v = fmaxf(v, __shfl_xor(v, o, 64));
    if ((threadIdx.x & 63) == 0) atomicMax((unsigned int*)addr, __float_as_uint(v));
}

__global__ void kz(float* ws) {
    int t = threadIdx.x;
    if (t < BB * 32) ws[ACC_OFF + t] = 0.f;
    if (t < BB) ((unsigned int*)(ws + CNT_OFF))[t] = 0u;
}

__global__ void k1(const float* __restrict__ logits, const float* __restrict__ olog,
                   const float* __restrict__ h, const int* __restrict__ tgt,
                   const float* __restrict__ pts, float* __restrict__ ws) {
    int gid = blockIdx.x * 256 + threadIdx.x;   // over BB*NN
    int b = gid / NN;
    int lane = threadIdx.x & 63;

    const float* L = logits + (size_t)gid * 3;
    float l0 = L[0], l1 = L[1], l2 = L[2];
    const float* O = olog + (size_t)gid * 3;
    float o0 = O[0], o1 = O[1], o2 = O[2];
    float hp = h[gid];
    int t = tgt[gid];
    const float* P = pts + (size_t)gid * 3;
    float px = P[0], py = P[1], pz = P[2];

    // softmax + log-softmax of logits
    float m = fmaxf(l0, fmaxf(l1, l2));
    float e0 = expf(l0 - m), e1 = expf(l1 - m), e2 = expf(l2 - m);
    float s = e0 + e1 + e2;
    float inv = 1.f / s;
    float p0 = e0 * inv, p1 = e1 * inv, p2 = e2 * inv;
    float ls = logf(s);
    float lt = (t == 0) ? l0 : ((t == 1) ? l1 : l2);
    float nll = -(lt - m - ls);

    // softmax of original logits
    float mo = fmaxf(o0, fmaxf(o1, o2));
    float f0 = expf(o0 - mo), f1 = expf(o1 - mo), f2 = expf(o2 - mo);
    float so = 1.f / (f0 + f1 + f2);
    float q0 = f0 * so, q1 = f1 * so, q2 = f2 * so;

    float con = (p0 - q0) * (p0 - q0) + (p1 - q1) * (p1 - q1) + (p2 - q2) * (p2 - q2);

    float bm = (hp > 0.3f && hp < 0.7f) ? 1.f : 0.f;
    float w = 1.f + bm;
    float refc = nll * w;

    float pred = (l2 > l0 && l2 > l1) ? 1.f : 0.f;
    float gt = (t == 2) ? 1.f : 0.f;

    // compact boundary points: ONE atomic per wave (wave never straddles b)
    unsigned long long mask = __ballot(bm > 0.f);
    unsigned int base = 0;
    if (lane == 0 && mask)
        base = atomicAdd(((unsigned int*)(ws + CNT_OFF)) + b, (unsigned int)__popcll(mask));
    base = __shfl((int)base, 0, 64);
    if (bm > 0.f) {
        unsigned int idx = base + __popcll(mask & ((1ull << lane) - 1ull));
        float4* cd = (float4*)(ws + CDATA_OFF);
        cd[(size_t)b * NN + idx] = make_float4(px, py, pz, p2);
    }
    ws[PM_OFF + gid] = pred;

    float* a = ws + ACC_OFF + b * 32;
    wave_atomic_add(a + 0, refc);
    wave_atomic_add(a + 1, con);
    wave_atomic_add(a + 2, pred);
    wave_atomic_add(a + 3, pred * px);
    wave_atomic_add(a + 4, pred * py);
    wave_atomic_add(a + 5, pred * pz);
    wave_atomic_add(a + 6, gt);
    wave_atomic_add(a + 7, bm);
}

__global__ void k2(const float* __restrict__ pts, float* __restrict__ ws) {
    int gid = blockIdx.x * 256 + threadIdx.x;
    int b = gid / NN;
    float* a = ws + ACC_OFF + b * 32;

    float n = a[2];
    float nz = fmaxf(n, 1.f);
    float cx = a[3] / nz, cy = a[4] / nz, cz = a[5] / nz;

    const float* P = pts + (size_t)gid * 3;
    float dx = P[0] - cx, dy = P[1] - cy, dz = P[2] - cz;
    float mM = ws[PM_OFF + gid];

    float mx = dx * mM, my = dy * mM, mz = dz * mM;
    float d = sqrtf(dx * dx + dy * dy + dz * dz + 1e-12f);
    float dm = d * mM;

    wave_atomic_add(a + 8,  mx * mx);
    wave_atomic_add(a + 9,  mx * my);
    wave_atomic_add(a + 10, mx * mz);
    wave_atomic_add(a + 11, my * my);
    wave_atomic_add(a + 12, my * mz);
    wave_atomic_add(a + 13, mz * mz);
    wave_atomic_add(a + 14, dm);
    wave_atomic_add(a + 15, d * dm);
    wave_atomic_max_nonneg(a + 16, dm);
}

// pairwise over compacted boundary points
__global__ void k3(float* __restrict__ ws) {
    int bid = blockIdx.x;
    int js = bid % JSPLIT;
    int ib = (bid / JSPLIT) % (NN / 256);
    int b  = bid / (JSPLIT * (NN / 256));

    int M = (int)((unsigned int*)(ws + CNT_OFF))[b];
    if (ib * 256 >= M) return;                       // uniform block exit
    int chunk = (M + JSPLIT - 1) / JSPLIT;
    int jbeg = js * chunk;
    if (jbeg >= M) return;                           // uniform block exit
    int jend = min(jbeg + chunk, M);

    const float4* cd = (const float4*)(ws + CDATA_OFF) + (size_t)b * NN;
    int i = ib * 256 + threadIdx.x;
    bool active = (i < M);

    float4 me = cd[active ? i : 0];
    float xi = active ? me.x : 1e9f;
    float yi = me.y, zi = me.z;

    __shared__ float4 sj[TJ];
    float cnt = 0.f, s1 = 0.f, s2 = 0.f;

    for (int j0 = jbeg; j0 < jend; j0 += TJ) {
        int count = min(TJ, jend - j0);
        __syncthreads();
        for (int k = threadIdx.x; k < count; k += 256) sj[k] = cd[j0 + k];
        __syncthreads();
#pragma unroll 4
        for (int k = 0; k < count; k++) {
            float4 v = sj[k];
            float dx = xi - v.x, dy = yi - v.y, dz = zi - v.z;
            float d2 = dx * dx + dy * dy + dz * dz;
            if (d2 < 0.0025f) { cnt += 1.f; s1 += v.w; s2 += v.w * v.w; }
        }
    }

    if (active) {
        float* p = ws + PARTIAL_OFF + ((size_t)js * BB * NN + (size_t)b * NN + i) * 3;
        p[0] = cnt; p[1] = s1; p[2] = s2;
    }
}

__global__ void k4(float* __restrict__ ws) {
    int gid = blockIdx.x * 256 + threadIdx.x;
    int b = gid / NN;
    int i = gid % NN;

    int M = (int)((unsigned int*)(ws + CNT_OFF))[b];
    if ((gid % NN) - threadIdx.x >= M) return;       // uniform: whole block beyond M
    bool active = (i < M);
    int chunk = (M + JSPLIT - 1) / JSPLIT;

    float cnt = 0.f, s1 = 0.f, s2 = 0.f;
#pragma unroll
    for (int js = 0; js < JSPLIT; js++) {
        if (js * chunk < M && active) {
            const float* p = ws + PARTIAL_OFF + ((size_t)js * BB * NN + (size_t)b * NN + i) * 3;
            cnt += p[0]; s1 += p[1]; s2 += p[2];
        }
    }
    float var = (s2 - s1 * s1 / fmaxf(cnt, 1.f)) / fmaxf(cnt - 1.f, 1.f);
    float valid = (active && cnt > 1.f) ? 1.f : 0.f;

    float* a = ws + ACC_OFF + b * 32;
    wave_atomic_add(a + 17, var * valid);
    wave_atomic_add(a + 18, valid);
}

__global__ void k5(const float* __restrict__ ws, float* __restrict__ out) {
    if (threadIdx.x != 0 || blockIdx.x != 0) return;
    double tot = 0.0;
    for (int b = 0; b < BB; b++) {
        const float* a = ws + ACC_OFF + b * 32;
        double refm = (double)a[0] / NN;
        double conm = (double)a[1] / (NN * 3);
        double n = a[2];
        double nz = fmax(n, 1.0);

        double shape = 0.0;
        if (n >= 10.0) {
            double cxx = a[8] / nz, cxy = a[9] / nz, cxz = a[10] / nz;
            double cyy = a[11] / nz, cyz = a[12] / nz, czz = a[13] / nz;
            double q = (cxx + cyy + czz) / 3.0;
            double p1 = cxy * cxy + cxz * cxz + cyz * cyz;
            double p2 = (cxx - q) * (cxx - q) + (cyy - q) * (cyy - q) + (czz - q) * (czz - q) + 2.0 * p1;
            double p = sqrt(fmax(p2, 0.0) / 6.0);
            double ev0, ev1, ev2;
            if (p < 1e-30) { ev0 = ev1 = ev2 = q; }
            else {
                double b00 = (cxx - q) / p, b11 = (cyy - q) / p, b22 = (czz - q) / p;
                double b01 = cxy / p, b02 = cxz / p, b12 = cyz / p;
                double det = b00 * (b11 * b22 - b12 * b12)
                           - b01 * (b01 * b22 - b12 * b02)
                           + b02 * (b01 * b12 - b11 * b02);
                double r = det / 2.0;
                r = fmin(1.0, fmax(-1.0, r));
                double phi = acos(r) / 3.0;
                double e1 = q + 2.0 * p * cos(phi);
                double e3 = q + 2.0 * p * cos(phi + 2.0943951023931953);
                double e2 = 3.0 * q - e1 - e3;
                ev2 = e1; ev1 = e2; ev0 = e3;
            }
            double aa = ev2 + 1e-8;
            double r1 = ev1 / aa - 1.0, r0 = ev0 / aa - 1.0;
            shape = r1 * r1 + r0 * r0;
        }

        double sdm = a[14], sd2m = a[15], maxd = a[16];
        double var = (sd2m - sdm * sdm / nz) / fmax(n - 1.0, 1.0);
        double conn = (n >= 5.0) ? var / (maxd + 1e-8) : 0.0;

        double sm = (a[7] >= 5.0) ? (double)a[17] / fmax((double)a[18], 1.0) : 0.0;

        double pv = a[2], gv = a[6];
        double vol = (pv - gv) * (pv - gv);
        double rel = fabs(pv - gv) / fmax(gv, 1.0);
        double size = (gv > 0.0) ? vol + 0.5 * rel : vol;

        tot += 0.3 * refm + 0.2 * conm + 0.5 * shape + 0.3 * sm + 0.8 * size + 0.6 * conn;
    }
    out[0] = (float)(tot / BB);
}

extern "C" void kernel_launch(void* const* d_in, const int* in_sizes, int n_in,
                              void* d_out, int out_size, void* d_ws, size_t ws_size,
                              hipStream_t stream) {
    const float* logits = (const float*)d_in[0];
    const float* olog   = (const float*)d_in[1];
    const float* h      = (const float*)d_in[2];
    const int*   tgt    = (const int*)d_in[3];
    const float* pts    = (const float*)d_in[4];
    float* out = (float*)d_out;
    float* ws  = (float*)d_ws;

    kz<<<1, 64, 0, stream>>>(ws);
    k1<<<BB * NN / 256, 256, 0, stream>>>(logits, olog, h, tgt, pts, ws);
    k2<<<BB * NN / 256, 256, 0, stream>>>(pts, ws);
    k3<<<BB * (NN / 256) * JSPLIT, 256, 0, stream>>>(ws);
    k4<<<BB * NN / 256, 256, 0, stream>>>(ws);
    k5<<<1, 64, 0, stream>>>(ws, out);
}